// Round 8
// baseline (49.509 us; speedup 1.0000x reference)
//
#include <hip/hip_runtime.h>

// Chamfer loss: B=4, N=M=8192, D=3, fp32 in, scalar fp32 out.
// loss = mean_n min_m ||x_n-y_m||^2 + mean_m min_n ||...||^2 + lambda*bpp
//
// R7: R6's MFMA formulation was B-fragment-delivery bound (32 rows/wave
// -> 1 MFMA per 1KB B load -> 536MB L1 traffic, 2 waves/SIMD). Now:
//   - 64 rows/wave (2 A frags): 2 MFMAs per B fragment (268MB traffic)
//   - col-tiles processed in pairs, merged via v_min3 (half the min VALU)
//   - 4-way col-segment split -> 1024 blocks, 4096 waves (~4/SIMD TLP);
//     per-segment partial mins are plain stores (1MB), folded in reduce1.
// Math (verified bit-exact in R6): P = y2 - 2 x.y by one
// v_mfma_f32_32x32x16_bf16 per 32x32 tile via split-bf16:
//   k0-2: -2xhi*yhi  k3: 1*y2hi  k4-6: -2xlo*yhi  k7: 1*y2lo
//   k8-10: -2xhi*ylo k11-15: 0
// C/D layout: col=lane&31, row=(q&3)+8*(q>>2)+4*(lane>>5).

typedef float  f16v __attribute__((ext_vector_type(16)));
typedef short  s8   __attribute__((ext_vector_type(8)));

#define NPTS   8192
#define NB     4
#define NPTOT  (NB * NPTS)        // 32768 points per cloud
#define NSEG   4                  // column-segment split
#define RBLK   128

__device__ __forceinline__ ushort f2bf(float f) {
    uint u = __float_as_uint(f);
    u += 0x7FFF + ((u >> 16) & 1);          // round-to-nearest-even
    return (ushort)(u >> 16);
}
__device__ __forceinline__ float bf2f(ushort h) {
    return __uint_as_float(((uint)h) << 16);
}
__device__ __forceinline__ uint pk(ushort lo, ushort hi) {
    return (uint)lo | ((uint)hi << 16);
}

// prep: per point (both clouds): split coords and ||p||^2 into bf16 hi/lo,
// store A-side records (rows) and B-side records (cols), 2 x uint4 each.
__global__ __launch_bounds__(256) void prep(
        const float* __restrict__ X, const float* __restrict__ Y,
        uint4* __restrict__ Arec, uint4* __restrict__ Brec) {
    int i = blockIdx.x * 256 + threadIdx.x;
    if (i >= 2 * NPTOT) return;
    const float* src = (i < NPTOT) ? X : Y;
    int p = i & (NPTOT - 1);
    float x0 = src[3*p], x1 = src[3*p+1], x2 = src[3*p+2];
    float n2 = __fmaf_rn(x0, x0, __fmaf_rn(x1, x1, x2 * x2));

    ushort h0 = f2bf(x0), h1 = f2bf(x1), h2 = f2bf(x2);
    ushort l0 = f2bf(x0 - bf2f(h0));
    ushort l1 = f2bf(x1 - bf2f(h1));
    ushort l2 = f2bf(x2 - bf2f(h2));
    ushort n2h = f2bf(n2);
    ushort n2l = f2bf(n2 - bf2f(n2h));
    ushort a0 = f2bf(-2.0f * bf2f(h0)), a1 = f2bf(-2.0f * bf2f(h1));
    ushort a2 = f2bf(-2.0f * bf2f(h2));
    ushort b0 = f2bf(-2.0f * bf2f(l0)), b1 = f2bf(-2.0f * bf2f(l1));
    ushort b2 = f2bf(-2.0f * bf2f(l2));
    const ushort ONE = 0x3F80;

    Arec[(size_t)i*2 + 0] = make_uint4(pk(a0,a1), pk(a2,ONE), pk(b0,b1), pk(b2,ONE));
    Arec[(size_t)i*2 + 1] = make_uint4(pk(a0,a1), pk(a2,0),   0,          0);
    Brec[(size_t)i*2 + 0] = make_uint4(pk(h0,h1), pk(h2,n2h), pk(h0,h1), pk(h2,n2l));
    Brec[(size_t)i*2 + 1] = make_uint4(pk(l0,l1), pk(l2,0),   0,          0);
}

// load a pair of adjacent col-tile fragments (16B/lane each, coalesced)
#define LOADP(P, p)                                                        \
    P[0] = *(const s8*)(Bseg + (size_t)(2 * (p)) * 64 + boff);             \
    P[1] = *(const s8*)(Bseg + (size_t)(2 * (p) + 1) * 64 + boff);

// 4 MFMAs (2 row-frags x 2 col-tiles), merge via min3
#define COMP(P)                                                            \
    {                                                                      \
        f16v a00 = __builtin_amdgcn_mfma_f32_32x32x16_bf16(A0, P[0], zero16, 0, 0, 0); \
        f16v a01 = __builtin_amdgcn_mfma_f32_32x32x16_bf16(A0, P[1], zero16, 0, 0, 0); \
        f16v a10 = __builtin_amdgcn_mfma_f32_32x32x16_bf16(A1, P[0], zero16, 0, 0, 0); \
        f16v a11 = __builtin_amdgcn_mfma_f32_32x32x16_bf16(A1, P[1], zero16, 0, 0, 0); \
        _Pragma("unroll")                                                  \
        for (int q = 0; q < 16; q++) {                                     \
            racc0[q] = fminf(fminf(a00[q], a01[q]), racc0[q]);             \
            racc1[q] = fminf(fminf(a10[q], a11[q]), racc1[q]);             \
        }                                                                  \
    }

__global__ __launch_bounds__(256) void mfma_pass(
        const uint4* __restrict__ Arec, const uint4* __restrict__ Brec,
        float* __restrict__ minsP) {
    // grid = 1024: pass(2) x batch(4) x rowblk(32) x seg(4)
    // block = 4 waves; wave owns 64 rows x one 2048-col segment
    int bid    = blockIdx.x;
    int pass   = bid >> 9;
    int r      = bid & 511;
    int b      = r >> 7;
    int rem    = r & 127;
    int rowblk = rem >> 2;
    int seg    = rem & 3;
    int lane   = threadIdx.x & 63;
    int wave   = threadIdx.x >> 6;
    int ca     = pass;              // A-cloud: 0=X,1=Y
    int cb     = 1 - pass;
    int ibase  = (rowblk * 4 + wave) * 64;

    // two A fragments: rows [ibase, ibase+32) and [ibase+32, ibase+64)
    size_t pA = (size_t)ca * NPTOT + b * NPTS + ibase + (lane & 31);
    int krec = lane >> 5;
    s8 A0 = *(const s8*)&Arec[(pA)      * 2 + krec];
    s8 A1 = *(const s8*)&Arec[(pA + 32) * 2 + krec];

    // B segment: 64 col-tiles of 32 points (64 recs of 16B each)
    const uint4* Bseg = Brec + ((size_t)cb * NPTOT + (size_t)b * NPTS) * 2
                      + (size_t)seg * 64 * 64;
    int boff = (lane & 31) * 2 + krec;

    const f16v zero16 = {0,0,0,0,0,0,0,0,0,0,0,0,0,0,0,0};
    f16v racc0, racc1;
#pragma unroll
    for (int q = 0; q < 16; q++) { racc0[q] = 3.0e38f; racc1[q] = 3.0e38f; }

    // 32 col-tile pairs, ping-pong prefetch
    s8 PA[2], PB[2];
    LOADP(PA, 0);
    for (int p = 0; p < 30; p += 2) {
        LOADP(PB, p + 1);
        COMP(PA);
        LOADP(PA, p + 2);
        COMP(PB);
    }
    LOADP(PB, 31);
    COMP(PA);
    COMP(PB);

    // row-min across 32 cols (lane bits 0-4), then plain store per segment
    float* dst = minsP + ((size_t)seg * 2 + pass) * NPTOT + (size_t)b * NPTS;
    int half = lane >> 5;
#pragma unroll
    for (int h2 = 0; h2 < 2; h2++) {
#pragma unroll
        for (int q = 0; q < 16; q++) {
            float v = h2 ? racc1[q] : racc0[q];
            v = fminf(v, __shfl_xor(v, 1, 64));
            v = fminf(v, __shfl_xor(v, 2, 64));
            v = fminf(v, __shfl_xor(v, 4, 64));
            v = fminf(v, __shfl_xor(v, 8, 64));
            v = fminf(v, __shfl_xor(v, 16, 64));
            if ((lane & 31) == 0)
                dst[ibase + h2 * 32 + (q & 3) + 8 * (q >> 2) + 4 * half] = v;
        }
    }
}

__global__ __launch_bounds__(256) void reduce1(
        const float* __restrict__ minsP,
        const float* __restrict__ X, const float* __restrict__ Y,
        float2* __restrict__ out2) {
    __shared__ float s1[256], s2[256];
    int t = threadIdx.x;
    int i = blockIdx.x * 256 + t;           // RBLK*256 == NPTOT exactly
    float mx = 3.0e38f, my = 3.0e38f;
#pragma unroll
    for (int s = 0; s < NSEG; s++) {
        mx = fminf(mx, minsP[((size_t)s * 2 + 0) * NPTOT + i]);
        my = fminf(my, minsP[((size_t)s * 2 + 1) * NPTOT + i]);
    }
    float a = X[3*i], bb = X[3*i+1], c = X[3*i+2];
    float sx = mx + __fmaf_rn(a, a, __fmaf_rn(bb, bb, c * c));
    float d = Y[3*i], e = Y[3*i+1], f = Y[3*i+2];
    float sy = my + __fmaf_rn(d, d, __fmaf_rn(e, e, f * f));
    s1[t] = sx; s2[t] = sy;
    __syncthreads();
    for (int s = 128; s > 0; s >>= 1) {
        if (t < s) { s1[t] += s1[t + s]; s2[t] += s2[t + s]; }
        __syncthreads();
    }
    if (t == 0) out2[blockIdx.x] = make_float2(s1[0], s2[0]);
}

__global__ __launch_bounds__(RBLK) void reduce2(
        const float2* __restrict__ p2,
        const float* __restrict__ bpp, const float* __restrict__ lam,
        float* __restrict__ out) {
    __shared__ float s[RBLK];
    int t = threadIdx.x;
    float2 p = p2[t];
    s[t] = p.x + p.y;
    __syncthreads();
    for (int h = RBLK / 2; h > 0; h >>= 1) {
        if (t < h) s[t] += s[t + h];
        __syncthreads();
    }
    if (t == 0) out[0] = s[0] * (1.0f / (float)NPTOT) + lam[0] * bpp[0];
}

extern "C" void kernel_launch(void* const* d_in, const int* in_sizes, int n_in,
                              void* d_out, int out_size, void* d_ws, size_t ws_size,
                              hipStream_t stream) {
    const float* X   = (const float*)d_in[0];   // pc_pred  [4,8192,3]
    const float* Y   = (const float*)d_in[1];   // pc_target[4,8192,3]
    const float* bpp = (const float*)d_in[2];
    const float* lam = (const float*)d_in[3];
    float* out = (float*)d_out;

    char* w = (char*)d_ws;
    float2* p2    = (float2*)w;                 w += 1024;
    float*  minsP = (float*)w;                  w += (size_t)NSEG * 2 * NPTOT * sizeof(float);
    uint4*  Arec  = (uint4*)w;                  w += (size_t)2 * NPTOT * 2 * sizeof(uint4);
    uint4*  Brec  = (uint4*)w;

    prep<<<(2 * NPTOT + 255) / 256, 256, 0, stream>>>(X, Y, Arec, Brec);
    mfma_pass<<<1024, 256, 0, stream>>>(Arec, Brec, minsP);
    reduce1<<<RBLK, 256, 0, stream>>>(minsP, X, Y, p2);
    reduce2<<<1, RBLK, 0, stream>>>(p2, bpp, lam, out);
}